// Round 2
// baseline (765.090 us; speedup 1.0000x reference)
//
#include <hip/hip_runtime.h>
#include <hip/hip_fp16.h>
#include <math.h>

// NerfHead: fused ray-march + trilinear + online transmittance + 3 losses.
// One wave (64 lanes) per ray, 4 rays per 256-thread block.
// d_ws layout: [0..255]   float acc[7] (+pad)
//              [256.. ]   packed voxel records, 64 B each:
//                         dword0 = f32 density, dword1..9 = 17 f16 semantic
//                         (half2-packed) + 1 pad half, dword10..15 = 0.

#define DXX 200
#define DYY 200
#define DZZ 16
#define NC 17
#define S_TOT 416
#define N_IN 390
#define CHUNKS 7
#define RPB 4
#define NVOX (DXX * DYY * DZZ)     // 640000
#define REC_DW 16                  // dwords per record (64 B)
#define REC_BYTES ((size_t)NVOX * REC_DW * 4)

__constant__ double c_freq[NC] = {1163161.0, 2309034.0, 188743.0, 2997643.0,
  20317180.0, 852476.0, 243808.0, 2457947.0, 497017.0, 2731022.0, 7224789.0,
  214411435.0, 5565043.0, 63191967.0, 76098082.0, 128860031.0, 141625221.0};

__device__ __forceinline__ float iscan_add(float x, int lane) {
#pragma unroll
  for (int off = 1; off < 64; off <<= 1) {
    float y = __shfl_up(x, off);
    if (lane >= off) x += y;
  }
  return x;
}
__device__ __forceinline__ float iscan_mul(float x, int lane) {
#pragma unroll
  for (int off = 1; off < 64; off <<= 1) {
    float y = __shfl_up(x, off);
    if (lane >= off) x *= y;
  }
  return x;
}

__device__ __forceinline__ __half2 u2h(unsigned int u) {
  union { unsigned int u; __half2 h; } c;
  c.u = u;
  return c.h;
}
__device__ __forceinline__ unsigned int packh2(float a, float b) {
  union { __half2 h; unsigned int u; } c;
  c.h = __halves2half2(__float2half_rn(a), __float2half_rn(b));
  return c.u;
}

__global__ __launch_bounds__(256) void nerf_zero(float* acc) {
  if (threadIdx.x < 16) acc[threadIdx.x] = 0.f;
}

// ---- repack: [v][c] f32 semantic + f32 density -> 64B records in ws ----
__global__ __launch_bounds__(256) void nerf_repack(
    const float* __restrict__ density,
    const float* __restrict__ semantic,
    unsigned int* __restrict__ rec) {
  __shared__ float sf[256 * NC];
  size_t v0 = (size_t)blockIdx.x * 256;
  for (int i = threadIdx.x; i < 256 * NC; i += 256)
    sf[i] = semantic[v0 * NC + i];
  __syncthreads();
  size_t v = v0 + threadIdx.x;
  float d = density[v];
  const float* s = &sf[threadIdx.x * NC];
  unsigned int o[REC_DW];
  o[0] = __float_as_uint(d);
#pragma unroll
  for (int k = 0; k < 8; k++) o[1 + k] = packh2(s[2 * k], s[2 * k + 1]);
  o[9] = packh2(s[16], 0.f);
#pragma unroll
  for (int k = 10; k < REC_DW; k++) o[k] = 0u;
  uint4* dst = (uint4*)(rec + v * REC_DW);
  dst[0] = make_uint4(o[0], o[1], o[2], o[3]);
  dst[1] = make_uint4(o[4], o[5], o[6], o[7]);
  dst[2] = make_uint4(o[8], o[9], o[10], o[11]);
  dst[3] = make_uint4(o[12], o[13], o[14], o[15]);
}

template <int PACKED>
__global__ __launch_bounds__(256) void nerf_main(
    const float* __restrict__ density,
    const float* __restrict__ semantic,
    const unsigned int* __restrict__ rec,
    const float* __restrict__ rays,
    const float* __restrict__ bda,
    float* __restrict__ acc_g,
    int nrays) {
  __shared__ float s_t[CHUNKS * 64];
  __shared__ float s_dist[RPB][S_TOT];
  __shared__ unsigned long long s_keep[RPB][CHUNKS];

  const int lane = threadIdx.x & 63;
  const int wv = threadIdx.x >> 6;
  const int ray = blockIdx.x * RPB + wv;

  const double BG = (double)(1.0f / 39.0f);
  const float BGf = (float)BG;
  const float DTH = (float)((2.0 + 2.0 * BG) / 200.0 * 0.5 * 0.95);
  const float xminf = (float)(-1.0 - BG);
  const float xmaxf = (float)(1.0 + BG);
  const float zf = 6.4f / 80.0f;
  const float sxy = 199.0f / (xmaxf - xminf);
  const float szc = 15.0f / (zf + zf);
  const float ACTS = -13.815509557964274f;

  for (int i = threadIdx.x; i < CHUNKS * 64; i += 256) {
    double td;
    if (i < N_IN) {
      td = (2.0 * i + 1.0) / 390.0;
    } else {
      int j = i - N_IN;
      const double stp = (1.0 / 64.0 - 1.0) / 26.0;
      double l0 = 1.0 + j * stp;
      double l1 = (j + 1 >= 26) ? (1.0 / 64.0) : (1.0 + (j + 1) * stp);
      td = 1.0 / l0 + 1.0 / l1;
    }
    s_t[i] = (float)td;
  }
  __syncthreads();

  bool doit = false;
  float rox = 0, roy = 0, roz = 0, rdx = 0, rdy = 0, rdz = 0;
  float b00 = 0, b01 = 0, b02 = 0, b10 = 0, b11 = 0, b12 = 0, b20 = 0, b21 = 0, b22 = 0;
  int ysem = 0;
  if (ray < nrays) {
    const float* rp = rays + (size_t)ray * 10;
    float dep = rp[2];
    doit = (dep > 0.f) && (dep <= 52.f);
    ysem = (int)rp[3];
    ysem = ysem < 0 ? 0 : (ysem > NC - 1 ? NC - 1 : ysem);
    const float czc = (-1.0f + 5.4f) * 0.5f;
    rox = rp[4] / 39.0f;
    roy = rp[5] / 39.0f;
    roz = (rp[6] - czc) / 39.0f;
    float d0 = rp[7], d1 = rp[8], d2 = rp[9];
    float rn = sqrtf(d0 * d0 + d1 * d1 + d2 * d2);
    rdx = d0 / rn; rdy = d1 / rn; rdz = d2 / rn;
    b00 = bda[0]; b01 = bda[1]; b02 = bda[2];
    b10 = bda[3]; b11 = bda[4]; b12 = bda[5];
    b20 = bda[6]; b21 = bda[7]; b22 = bda[8];
  }

  auto compute_pt = [&](int s, float& tx, float& ty, float& tz, float& tt,
                        bool& inner) {
    tt = s_t[s];
    float qx = rox + rdx * tt;
    float qy = roy + rdy * tt;
    float qz = roz + rdz * tt;
    float nr = sqrtf(qx * qx + qy * qy + qz * qz);
    inner = (nr <= 1.0f) && (s < S_TOT);
    if (nr > 1.0f) {
      float sc = (1.0f + BGf - BGf / nr) / nr;
      qx *= sc; qy *= sc; qz *= sc;
    }
    tx = b00 * qx + b01 * qy + b02 * qz;
    ty = b10 * qx + b11 * qy + b12 * qz;
    tz = b20 * qx + b21 * qy + b22 * qz;
  };

  // ---- phase A/B: pts, inner ballot, consecutive distances -> LDS ----
  if (doit) {
    for (int c = 0; c < CHUNKS; c++) {
      int s = c * 64 + lane;
      float tx, ty, tz, tt; bool inner;
      compute_pt(s, tx, ty, tz, tt, inner);
      unsigned long long bal = __ballot(inner);
      if (lane == 0) s_keep[wv][c] = bal;
      float nx = __shfl(tx, lane + 1);
      float ny = __shfl(ty, lane + 1);
      float nz = __shfl(tz, lane + 1);
      if (c < CHUNKS - 1) {
        float hx, hy, hz, ht; bool hi;
        compute_pt((c + 1) * 64, hx, hy, hz, ht, hi);
        if (lane == 63) { nx = hx; ny = hy; nz = hz; }
      }
      if (s < S_TOT - 1) {
        float ex = nx - tx, ey = ny - ty, ez = nz - tz;
        s_dist[wv][s] = sqrtf(ex * ex + ey * ey + ez * ez);
      }
    }
  }
  __syncthreads();

  // ---- phase C: sequential resetting distance scan -> keep mask ----
  if (doit && lane == 0) {
    float cum = 0.f;
    for (int c = 0; c < CHUNKS; c++) {
      unsigned long long k = s_keep[wv][c];
      int b0 = (c == 0) ? 1 : 0;
      for (int b = b0; b < 64; b++) {
        int s = c * 64 + b;
        if (s >= S_TOT) break;
        cum += s_dist[wv][s - 1];
        if (cum > DTH) { cum = 0.f; k |= (1ull << b); }
      }
      s_keep[wv][c] = k;
    }
  }
  __syncthreads();

  // ---- phase D/E/F ----
  float out_sem[NC];
  if (doit) {
#pragma unroll
    for (int j = 0; j < NC; j++) out_sem[j] = 0.f;
    float carry = 1.f, carryW = 0.f, carryWM = 0.f;
    float sum_bi = 0.f, sum_w2 = 0.f, pkcf = 0.f;

    for (int c = 0; c < CHUNKS; c++) {
      int s = c * 64 + lane;
      float tx, ty, tz, tt; bool inner;
      compute_pt(s, tx, ty, tz, tt, inner);
      float m_ = 1.0f - 1.0f / (1.0f + tt);
      bool keep = (s_keep[wv][c] >> lane) & 1ull;

      float a = 0.f;
      float semf[NC];
#pragma unroll
      for (int j = 0; j < NC; j++) semf[j] = 0.f;

      if (keep) {
        float gx = (tx - xminf) * sxy;
        float gy = (ty - xminf) * sxy;
        float gz = (tz + zf) * szc;
        float hx = floorf(gx), hy = floorf(gy), hz = floorf(gz);
        int ix = (int)hx, iy = (int)hy, iz = (int)hz;
        float fx = gx - hx, fy = gy - hy, fz = gz - hz;
        bool any = (ix >= -1) && (ix <= DXX - 1) && (iy >= -1) &&
                   (iy <= DYY - 1) && (iz >= -1) && (iz <= DZZ - 1);
        float dens = 0.f;
        if (any) {
          int x0 = ix < 0 ? 0 : ix;
          int x1 = (ix + 1 > DXX - 1) ? DXX - 1 : ix + 1;
          int y0 = iy < 0 ? 0 : iy;
          int y1 = (iy + 1 > DYY - 1) ? DYY - 1 : iy + 1;
          int z0 = iz < 0 ? 0 : iz;
          int z1 = (iz + 1 > DZZ - 1) ? DZZ - 1 : iz + 1;
          float wxm[2] = {(ix >= 0) ? 1.f - fx : 0.f,
                          (ix + 1 <= DXX - 1) ? fx : 0.f};
          float wym[2] = {(iy >= 0) ? 1.f - fy : 0.f,
                          (iy + 1 <= DYY - 1) ? fy : 0.f};
          float wzm[2] = {(iz >= 0) ? 1.f - fz : 0.f,
                          (iz + 1 <= DZZ - 1) ? fz : 0.f};
          int xs[2] = {x0 * (DYY * DZZ), x1 * (DYY * DZZ)};
          int ys[2] = {y0 * DZZ, y1 * DZZ};
          int zs[2] = {z0, z1};
          if (PACKED) {
            __half2 sacc[9];
#pragma unroll
            for (int k = 0; k < 9; k++) sacc[k] = u2h(0u);
#pragma unroll
            for (int dx = 0; dx < 2; dx++) {
#pragma unroll
              for (int dy = 0; dy < 2; dy++) {
#pragma unroll
                for (int dz = 0; dz < 2; dz++) {
                  float wc = wxm[dx] * wym[dy] * wzm[dz];
                  size_t idx = (size_t)(xs[dx] + ys[dy] + zs[dz]);
                  const uint4* p4 = (const uint4*)(rec + idx * REC_DW);
                  uint4 A = p4[0];
                  uint4 B = p4[1];
                  uint2 C = *(const uint2*)(rec + idx * REC_DW + 8);
                  dens = fmaf(wc, __uint_as_float(A.x), dens);
                  __half2 w2 = __float2half2_rn(wc);
                  sacc[0] = __hfma2(w2, u2h(A.y), sacc[0]);
                  sacc[1] = __hfma2(w2, u2h(A.z), sacc[1]);
                  sacc[2] = __hfma2(w2, u2h(A.w), sacc[2]);
                  sacc[3] = __hfma2(w2, u2h(B.x), sacc[3]);
                  sacc[4] = __hfma2(w2, u2h(B.y), sacc[4]);
                  sacc[5] = __hfma2(w2, u2h(B.z), sacc[5]);
                  sacc[6] = __hfma2(w2, u2h(B.w), sacc[6]);
                  sacc[7] = __hfma2(w2, u2h(C.x), sacc[7]);
                  sacc[8] = __hfma2(w2, u2h(C.y), sacc[8]);
                }
              }
            }
#pragma unroll
            for (int k = 0; k < 8; k++) {
              float2 f = __half22float2(sacc[k]);
              semf[2 * k] = f.x;
              semf[2 * k + 1] = f.y;
            }
            semf[16] = __low2float(sacc[8]);
          } else {
#pragma unroll
            for (int dx = 0; dx < 2; dx++) {
#pragma unroll
              for (int dy = 0; dy < 2; dy++) {
#pragma unroll
                for (int dz = 0; dz < 2; dz++) {
                  float wc = wxm[dx] * wym[dy] * wzm[dz];
                  size_t idx = (size_t)(xs[dx] + ys[dy] + zs[dz]);
                  dens = fmaf(wc, density[idx], dens);
                  const float* sp = semantic + idx * NC;
#pragma unroll
                  for (int j = 0; j < NC; j++)
                    semf[j] = fmaf(wc, sp[j], semf[j]);
                }
              }
            }
          }
        }
        float u = expf(dens + ACTS);
        a = -expm1f(-0.5f * log1pf(u));
        if (!(a > 1e-7f)) a = 0.f;
      }

      // transmittance cumprod (chunked scan + carry)
      float om = 1.f - a;
      float ip = iscan_mul(om, lane);
      float ex = __shfl_up(ip, 1); if (lane == 0) ex = 1.f;
      float wgt = a * carry * ex;
      carry *= __shfl(ip, 63);
      float w = (wgt > 1e-7f) ? wgt : 0.f;
      if (w > 0.f) pkcf += 1.f;

      // distortion-loss cumsums (exclusive)
      float wm = w * m_;
      float isw = iscan_add(w, lane);
      float iswm = iscan_add(wm, lane);
      float exw = __shfl_up(isw, 1);  if (lane == 0) exw = 0.f;
      float exwm = __shfl_up(iswm, 1); if (lane == 0) exwm = 0.f;
      sum_bi += 2.f * w * (m_ * (carryW + exw) - (carryWM + exwm));
      sum_w2 += w * w;
      carryW += __shfl(isw, 63);
      carryWM += __shfl(iswm, 63);

      // semantic accumulation
#pragma unroll
      for (int j = 0; j < NC; j++) out_sem[j] = fmaf(w, semf[j], out_sem[j]);
    }

    // ---- wave reductions + per-ray epilogue + atomics ----
    float r0 = sum_bi, r1 = sum_w2, r2 = pkcf;
#pragma unroll
    for (int off = 32; off >= 1; off >>= 1) {
      r0 += __shfl_xor(r0, off);
      r1 += __shfl_xor(r1, off);
      r2 += __shfl_xor(r2, off);
#pragma unroll
      for (int j = 0; j < NC; j++) out_sem[j] += __shfl_xor(out_sem[j], off);
    }
    if (lane == 0) {
      float M = out_sem[0];
#pragma unroll
      for (int j = 1; j < NC; j++) M = fmaxf(M, out_sem[j]);
      float se = 0.f;
#pragma unroll
      for (int j = 0; j < NC; j++) se += expf(out_sem[j] - M);
      float lse = M + logf(se);
      float sy = 0.f;
#pragma unroll
      for (int j = 0; j < NC; j++) if (j == ysem) sy = out_sem[j];
      float nll = lse - sy;
      float cw = (float)(1.0 / log(c_freq[ysem] + 0.001));
      float p = fminf(fmaxf(carry, 1e-6f), 1.0f - 1e-6f);
      float ent = -(p * logf(p) + (1.f - p) * logf(1.f - p));
      atomicAdd(&acc_g[0], cw * nll);
      atomicAdd(&acc_g[1], cw);
      atomicAdd(&acc_g[2], ent);
      atomicAdd(&acc_g[3], 1.f);
      atomicAdd(&acc_g[4], r0);
      atomicAdd(&acc_g[5], r1);
      atomicAdd(&acc_g[6], r2);
    }
  }
}

__global__ __launch_bounds__(64) void nerf_fin(const float* __restrict__ acc,
                                               float* __restrict__ out) {
  if (threadIdx.x == 0) {
    float ls = acc[0] / fmaxf(acc[1], 1e-12f);
    float nv = fmaxf(acc[3], 1.f);
    float le = acc[2] / nv;
    float nmax = fmaxf(acc[6], 1.f);
    float ld = (acc[4] + (1.f / 3.f) * (1.f / nmax) * acc[5]) / nv;
    out[0] = 1.0f * ls;
    out[1] = 0.01f * le;
    out[2] = 0.01f * ld;
  }
}

extern "C" void kernel_launch(void* const* d_in, const int* in_sizes, int n_in,
                              void* d_out, int out_size, void* d_ws, size_t ws_size,
                              hipStream_t stream) {
  const float* density = (const float*)d_in[0];
  const float* semantic = (const float*)d_in[1];
  const float* rays = (const float*)d_in[2];
  const float* bda = (const float*)d_in[3];
  float* out = (float*)d_out;
  float* acc = (float*)d_ws;
  unsigned int* rec = (unsigned int*)((char*)d_ws + 256);
  int nrays = in_sizes[2] / 10;
  int nb = (nrays + RPB - 1) / RPB;

  nerf_zero<<<1, 256, 0, stream>>>(acc);
  if (ws_size >= 256 + REC_BYTES) {
    nerf_repack<<<NVOX / 256, 256, 0, stream>>>(density, semantic, rec);
    nerf_main<1><<<nb, 64 * RPB, 0, stream>>>(density, semantic, rec, rays,
                                              bda, acc, nrays);
  } else {
    nerf_main<0><<<nb, 64 * RPB, 0, stream>>>(density, semantic, rec, rays,
                                              bda, acc, nrays);
  }
  nerf_fin<<<1, 64, 0, stream>>>(acc, out);
}

// Round 3
// 757.491 us; speedup vs baseline: 1.0100x; 1.0100x over previous
//
#include <hip/hip_runtime.h>
#include <hip/hip_fp16.h>
#include <math.h>

// NerfHead: fused ray-march + trilinear + online transmittance + 3 losses.
// One wave per ray, 4 rays per 256-thread block.
// d_ws: [0..255] float acc[7]; [256..] optional 48-B voxel records:
//   dword0 = f32 density, dword1..9 = 17 f16 semantic (+pad), dword10..11 = 0.
// Records are 16-B aligned by construction (48 = 3*16).

#define DXX 200
#define DYY 200
#define DZZ 16
#define NC 17
#define S_TOT 416
#define N_IN 390
#define CHUNKS 7
#define RPB 4
#define NVOX (DXX * DYY * DZZ)
#define REC_DW 12
#define REC_BYTES ((size_t)NVOX * REC_DW * 4)   // 30,720,000

__constant__ double c_freq[NC] = {1163161.0, 2309034.0, 188743.0, 2997643.0,
  20317180.0, 852476.0, 243808.0, 2457947.0, 497017.0, 2731022.0, 7224789.0,
  214411435.0, 5565043.0, 63191967.0, 76098082.0, 128860031.0, 141625221.0};

__device__ __forceinline__ float iscan_add(float x, int lane) {
#pragma unroll
  for (int off = 1; off < 64; off <<= 1) {
    float y = __shfl_up(x, off);
    if (lane >= off) x += y;
  }
  return x;
}
__device__ __forceinline__ float iscan_mul(float x, int lane) {
#pragma unroll
  for (int off = 1; off < 64; off <<= 1) {
    float y = __shfl_up(x, off);
    if (lane >= off) x *= y;
  }
  return x;
}

__device__ __forceinline__ __half2 u2h(unsigned int u) {
  union { unsigned int u; __half2 h; } c;
  c.u = u;
  return c.h;
}
__device__ __forceinline__ unsigned int packh2(float a, float b) {
  union { __half2 h; unsigned int u; } c;
  c.h = __halves2half2(__float2half_rn(a), __float2half_rn(b));
  return c.u;
}

__global__ __launch_bounds__(256) void nerf_zero(float* acc) {
  if (threadIdx.x < 16) acc[threadIdx.x] = 0.f;
}

// ---- repack to 48-B records (only launched when ws_size allows) ----
__global__ __launch_bounds__(64) void nerf_repack(
    const float* __restrict__ density,
    const float* __restrict__ semantic,
    unsigned int* __restrict__ rec) {
  __shared__ float sf[64 * NC];
  __shared__ __align__(16) unsigned int so[64 * REC_DW];
  const int tid = threadIdx.x;
  const size_t v0 = (size_t)blockIdx.x * 64;
  for (int i = tid; i < 64 * NC; i += 64) sf[i] = semantic[v0 * NC + i];
  float d = density[v0 + tid];
  __syncthreads();
  const float* s = &sf[tid * NC];
  unsigned int* o = &so[tid * REC_DW];
  o[0] = __float_as_uint(d);
#pragma unroll
  for (int k = 0; k < 8; k++) o[1 + k] = packh2(s[2 * k], s[2 * k + 1]);
  o[9] = packh2(s[16], 0.f);
  o[10] = 0u; o[11] = 0u;
  __syncthreads();
  uint4* dst = (uint4*)(rec + v0 * REC_DW);
  const uint4* src = (const uint4*)so;
#pragma unroll
  for (int i = tid; i < 64 * REC_DW / 4; i += 64) dst[i] = src[i];
}

template <int PACKED>
__global__ __launch_bounds__(256) void nerf_main(
    const float* __restrict__ density,
    const float* __restrict__ semantic,
    const unsigned int* __restrict__ rec,
    const float* __restrict__ rays,
    const float* __restrict__ bda,
    float* __restrict__ acc_g,
    int nrays) {
  __shared__ float s_t[CHUNKS * 64];
  __shared__ float s_dist[RPB][S_TOT];
  __shared__ unsigned long long s_keep[RPB][CHUNKS];

  const int lane = threadIdx.x & 63;
  const int wv = threadIdx.x >> 6;
  const int ray = blockIdx.x * RPB + wv;

  const double BG = (double)(1.0f / 39.0f);
  const float BGf = (float)BG;
  const float DTH = (float)((2.0 + 2.0 * BG) / 200.0 * 0.5 * 0.95);
  const float xminf = (float)(-1.0 - BG);
  const float xmaxf = (float)(1.0 + BG);
  const float zf = 6.4f / 80.0f;
  const float sxy = 199.0f / (xmaxf - xminf);
  const float szc = 15.0f / (zf + zf);
  const float ACTS = -13.815509557964274f;

  for (int i = threadIdx.x; i < CHUNKS * 64; i += 256) {
    double td;
    if (i < N_IN) {
      td = (2.0 * i + 1.0) / 390.0;
    } else {
      int j = i - N_IN;
      const double stp = (1.0 / 64.0 - 1.0) / 26.0;
      double l0 = 1.0 + j * stp;
      double l1 = (j + 1 >= 26) ? (1.0 / 64.0) : (1.0 + (j + 1) * stp);
      td = 1.0 / l0 + 1.0 / l1;
    }
    s_t[i] = (float)td;
  }
  __syncthreads();

  bool doit = false;
  float rox = 0, roy = 0, roz = 0, rdx = 0, rdy = 0, rdz = 0;
  float b00 = 0, b01 = 0, b02 = 0, b10 = 0, b11 = 0, b12 = 0, b20 = 0, b21 = 0, b22 = 0;
  int ysem = 0;
  if (ray < nrays) {
    const float* rp = rays + (size_t)ray * 10;
    float dep = rp[2];
    doit = (dep > 0.f) && (dep <= 52.f);
    ysem = (int)rp[3];
    ysem = ysem < 0 ? 0 : (ysem > NC - 1 ? NC - 1 : ysem);
    const float czc = (-1.0f + 5.4f) * 0.5f;
    rox = rp[4] / 39.0f;
    roy = rp[5] / 39.0f;
    roz = (rp[6] - czc) / 39.0f;
    float d0 = rp[7], d1 = rp[8], d2 = rp[9];
    float rn = sqrtf(d0 * d0 + d1 * d1 + d2 * d2);
    rdx = d0 / rn; rdy = d1 / rn; rdz = d2 / rn;
    b00 = bda[0]; b01 = bda[1]; b02 = bda[2];
    b10 = bda[3]; b11 = bda[4]; b12 = bda[5];
    b20 = bda[6]; b21 = bda[7]; b22 = bda[8];
  }

  auto compute_pt = [&](int s, float& tx, float& ty, float& tz, float& tt,
                        bool& inner) {
    tt = s_t[s];
    float qx = rox + rdx * tt;
    float qy = roy + rdy * tt;
    float qz = roz + rdz * tt;
    float nr = sqrtf(qx * qx + qy * qy + qz * qz);
    inner = (nr <= 1.0f) && (s < S_TOT);
    if (nr > 1.0f) {
      float sc = (1.0f + BGf - BGf / nr) / nr;
      qx *= sc; qy *= sc; qz *= sc;
    }
    tx = b00 * qx + b01 * qy + b02 * qz;
    ty = b10 * qx + b11 * qy + b12 * qz;
    tz = b20 * qx + b21 * qy + b22 * qz;
  };

  // ---- phase A/B: pts, inner ballot, consecutive distances -> LDS ----
  if (doit) {
    for (int c = 0; c < CHUNKS; c++) {
      int s = c * 64 + lane;
      float tx, ty, tz, tt; bool inner;
      compute_pt(s, tx, ty, tz, tt, inner);
      unsigned long long bal = __ballot(inner);
      if (lane == 0) s_keep[wv][c] = bal;
      float nx = __shfl(tx, lane + 1);
      float ny = __shfl(ty, lane + 1);
      float nz = __shfl(tz, lane + 1);
      if (c < CHUNKS - 1) {
        float hx, hy, hz, ht; bool hi;
        compute_pt((c + 1) * 64, hx, hy, hz, ht, hi);
        if (lane == 63) { nx = hx; ny = hy; nz = hz; }
      }
      if (s < S_TOT - 1) {
        float ex = nx - tx, ey = ny - ty, ez = nz - tz;
        s_dist[wv][s] = sqrtf(ex * ex + ey * ey + ez * ez);
      }
    }
  }
  __syncthreads();

  // ---- phase C: sequential resetting distance scan -> keep mask ----
  if (doit && lane == 0) {
    float cum = 0.f;
    for (int c = 0; c < CHUNKS; c++) {
      unsigned long long k = s_keep[wv][c];
      int b0 = (c == 0) ? 1 : 0;
      for (int b = b0; b < 64; b++) {
        int s = c * 64 + b;
        if (s >= S_TOT) break;
        cum += s_dist[wv][s - 1];
        if (cum > DTH) { cum = 0.f; k |= (1ull << b); }
      }
      s_keep[wv][c] = k;
    }
  }
  __syncthreads();

  // ---- phase D/E/F ----
  float out_sem[NC];
  if (doit) {
#pragma unroll
    for (int j = 0; j < NC; j++) out_sem[j] = 0.f;
    float carry = 1.f, carryW = 0.f, carryWM = 0.f;
    float sum_bi = 0.f, sum_w2 = 0.f, pkcf = 0.f;

    for (int c = 0; c < CHUNKS; c++) {
      int s = c * 64 + lane;
      float tx, ty, tz, tt; bool inner;
      compute_pt(s, tx, ty, tz, tt, inner);
      float m_ = 1.0f - 1.0f / (1.0f + tt);
      bool keep = (s_keep[wv][c] >> lane) & 1ull;

      float a = 0.f;
      int ix = 0, iy = 0, iz = 0;
      float fx = 0.f, fy = 0.f, fz = 0.f;
      bool any = false;
      __half2 sacc[9];
      if (PACKED) {
#pragma unroll
        for (int k = 0; k < 9; k++) sacc[k] = u2h(0u);
      }

      if (keep) {
        float gx = (tx - xminf) * sxy;
        float gy = (ty - xminf) * sxy;
        float gz = (tz + zf) * szc;
        float hx = floorf(gx), hy = floorf(gy), hz = floorf(gz);
        ix = (int)hx; iy = (int)hy; iz = (int)hz;
        fx = gx - hx; fy = gy - hy; fz = gz - hz;
        any = (ix >= -1) && (ix <= DXX - 1) && (iy >= -1) &&
              (iy <= DYY - 1) && (iz >= -1) && (iz <= DZZ - 1);
        float dens = 0.f;
        if (any) {
          int x0 = ix < 0 ? 0 : ix;
          int x1 = (ix + 1 > DXX - 1) ? DXX - 1 : ix + 1;
          int y0 = iy < 0 ? 0 : iy;
          int y1 = (iy + 1 > DYY - 1) ? DYY - 1 : iy + 1;
          int z0 = iz < 0 ? 0 : iz;
          int z1 = (iz + 1 > DZZ - 1) ? DZZ - 1 : iz + 1;
          float wxm[2] = {(ix >= 0) ? 1.f - fx : 0.f,
                          (ix + 1 <= DXX - 1) ? fx : 0.f};
          float wym[2] = {(iy >= 0) ? 1.f - fy : 0.f,
                          (iy + 1 <= DYY - 1) ? fy : 0.f};
          float wzm[2] = {(iz >= 0) ? 1.f - fz : 0.f,
                          (iz + 1 <= DZZ - 1) ? fz : 0.f};
          unsigned int xs[2] = {(unsigned)(x0 * (DYY * DZZ)), (unsigned)(x1 * (DYY * DZZ))};
          unsigned int ys[2] = {(unsigned)(y0 * DZZ), (unsigned)(y1 * DZZ)};
          unsigned int zs[2] = {(unsigned)z0, (unsigned)z1};
          if (PACKED) {
            // fused density+semantic gather from 48-B records
#pragma unroll
            for (int dx = 0; dx < 2; dx++) {
#pragma unroll
              for (int dy = 0; dy < 2; dy++) {
#pragma unroll
                for (int dz = 0; dz < 2; dz++) {
                  float wc = wxm[dx] * wym[dy] * wzm[dz];
                  unsigned int vox = xs[dx] + ys[dy] + zs[dz];
                  const unsigned int* rp = rec + (size_t)vox * REC_DW;
                  uint4 A = *(const uint4*)rp;
                  uint4 B = *(const uint4*)(rp + 4);
                  uint2 C = *(const uint2*)(rp + 8);
                  dens = fmaf(wc, __uint_as_float(A.x), dens);
                  __half2 w2 = __float2half2_rn(wc);
                  sacc[0] = __hfma2(w2, u2h(A.y), sacc[0]);
                  sacc[1] = __hfma2(w2, u2h(A.z), sacc[1]);
                  sacc[2] = __hfma2(w2, u2h(A.w), sacc[2]);
                  sacc[3] = __hfma2(w2, u2h(B.x), sacc[3]);
                  sacc[4] = __hfma2(w2, u2h(B.y), sacc[4]);
                  sacc[5] = __hfma2(w2, u2h(B.z), sacc[5]);
                  sacc[6] = __hfma2(w2, u2h(B.w), sacc[6]);
                  sacc[7] = __hfma2(w2, u2h(C.x), sacc[7]);
                  sacc[8] = __hfma2(w2, u2h(C.y), sacc[8]);
                }
              }
            }
          } else {
            // density only; semantic deferred until w is known
            dens += wxm[0] * wym[0] * wzm[0] * density[(size_t)(xs[0] + ys[0] + zs[0])];
            dens += wxm[0] * wym[0] * wzm[1] * density[(size_t)(xs[0] + ys[0] + zs[1])];
            dens += wxm[0] * wym[1] * wzm[0] * density[(size_t)(xs[0] + ys[1] + zs[0])];
            dens += wxm[0] * wym[1] * wzm[1] * density[(size_t)(xs[0] + ys[1] + zs[1])];
            dens += wxm[1] * wym[0] * wzm[0] * density[(size_t)(xs[1] + ys[0] + zs[0])];
            dens += wxm[1] * wym[0] * wzm[1] * density[(size_t)(xs[1] + ys[0] + zs[1])];
            dens += wxm[1] * wym[1] * wzm[0] * density[(size_t)(xs[1] + ys[1] + zs[0])];
            dens += wxm[1] * wym[1] * wzm[1] * density[(size_t)(xs[1] + ys[1] + zs[1])];
          }
        }
        float u = expf(dens + ACTS);
        a = -expm1f(-0.5f * log1pf(u));
        if (!(a > 1e-7f)) a = 0.f;
      }

      // transmittance cumprod (chunked scan + carry)
      float om = 1.f - a;
      float ip = iscan_mul(om, lane);
      float ex = __shfl_up(ip, 1); if (lane == 0) ex = 1.f;
      float wgt = a * carry * ex;
      carry *= __shfl(ip, 63);
      float w = (wgt > 1e-7f) ? wgt : 0.f;
      if (w > 0.f) pkcf += 1.f;

      // distortion-loss cumsums (exclusive)
      float wm = w * m_;
      float isw = iscan_add(w, lane);
      float iswm = iscan_add(wm, lane);
      float exw = __shfl_up(isw, 1);  if (lane == 0) exw = 0.f;
      float exwm = __shfl_up(iswm, 1); if (lane == 0) exwm = 0.f;
      sum_bi += 2.f * w * (m_ * (carryW + exw) - (carryWM + exwm));
      sum_w2 += w * w;
      carryW += __shfl(isw, 63);
      carryWM += __shfl(iswm, 63);

      // semantic accumulation (w folded in)
      if (w > 0.f) {
        if (PACKED) {
#pragma unroll
          for (int k = 0; k < 8; k++) {
            float2 f = __half22float2(sacc[k]);
            out_sem[2 * k] = fmaf(w, f.x, out_sem[2 * k]);
            out_sem[2 * k + 1] = fmaf(w, f.y, out_sem[2 * k + 1]);
          }
          out_sem[16] = fmaf(w, __low2float(sacc[8]), out_sem[16]);
        } else if (any) {
          int x0 = ix < 0 ? 0 : ix;
          int x1 = (ix + 1 > DXX - 1) ? DXX - 1 : ix + 1;
          int y0 = iy < 0 ? 0 : iy;
          int y1 = (iy + 1 > DYY - 1) ? DYY - 1 : iy + 1;
          int z0 = iz < 0 ? 0 : iz;
          int z1 = (iz + 1 > DZZ - 1) ? DZZ - 1 : iz + 1;
          float wxm[2] = {(ix >= 0) ? 1.f - fx : 0.f,
                          (ix + 1 <= DXX - 1) ? fx : 0.f};
          float wym[2] = {(iy >= 0) ? 1.f - fy : 0.f,
                          (iy + 1 <= DYY - 1) ? fy : 0.f};
          float wzm[2] = {(iz >= 0) ? 1.f - fz : 0.f,
                          (iz + 1 <= DZZ - 1) ? fz : 0.f};
          unsigned int xs[2] = {(unsigned)(x0 * (DYY * DZZ)), (unsigned)(x1 * (DYY * DZZ))};
          unsigned int ys[2] = {(unsigned)(y0 * DZZ), (unsigned)(y1 * DZZ)};
          unsigned int zs[2] = {(unsigned)z0, (unsigned)z1};
#pragma unroll
          for (int dx = 0; dx < 2; dx++) {
#pragma unroll
            for (int dy = 0; dy < 2; dy++) {
#pragma unroll
              for (int dz = 0; dz < 2; dz++) {
                float wcw = w * wxm[dx] * wym[dy] * wzm[dz];
                unsigned int vox = xs[dx] + ys[dy] + zs[dz];
                unsigned int boff = vox * (NC * 4u);  // byte offset, fits 32b
                // 16-B aligned 80-B window covering the 68-B row.
                // align16(boff)+80 <= boff+68 <= NVOX*68, so never OOB.
                const float4* bp =
                    (const float4*)((const char*)semantic + (boff & ~15u));
                float4 q0 = bp[0], q1 = bp[1], q2 = bp[2], q3 = bp[3], q4 = bp[4];
                float v[20] = {q0.x, q0.y, q0.z, q0.w, q1.x, q1.y, q1.z, q1.w,
                               q2.x, q2.y, q2.z, q2.w, q3.x, q3.y, q3.z, q3.w,
                               q4.x, q4.y, q4.z, q4.w};
                int off = (boff >> 2) & 3;
                bool o2 = (off & 2) != 0;
                bool o1 = (off & 1) != 0;
#pragma unroll
                for (int j = 0; j < NC; j++) {
                  float aa = o2 ? v[j + 2] : v[j];
                  float bb = o2 ? v[j + 3] : v[j + 1];
                  float val = o1 ? bb : aa;
                  out_sem[j] = fmaf(wcw, val, out_sem[j]);
                }
              }
            }
          }
        }
      }
    }

    // ---- wave reductions + per-ray epilogue + atomics ----
    float r0 = sum_bi, r1 = sum_w2, r2 = pkcf;
#pragma unroll
    for (int off = 32; off >= 1; off >>= 1) {
      r0 += __shfl_xor(r0, off);
      r1 += __shfl_xor(r1, off);
      r2 += __shfl_xor(r2, off);
#pragma unroll
      for (int j = 0; j < NC; j++) out_sem[j] += __shfl_xor(out_sem[j], off);
    }
    if (lane == 0) {
      float M = out_sem[0];
#pragma unroll
      for (int j = 1; j < NC; j++) M = fmaxf(M, out_sem[j]);
      float se = 0.f;
#pragma unroll
      for (int j = 0; j < NC; j++) se += expf(out_sem[j] - M);
      float lse = M + logf(se);
      float sy = 0.f;
#pragma unroll
      for (int j = 0; j < NC; j++) if (j == ysem) sy = out_sem[j];
      float nll = lse - sy;
      float cw = (float)(1.0 / log(c_freq[ysem] + 0.001));
      float p = fminf(fmaxf(carry, 1e-6f), 1.0f - 1e-6f);
      float ent = -(p * logf(p) + (1.f - p) * logf(1.f - p));
      atomicAdd(&acc_g[0], cw * nll);
      atomicAdd(&acc_g[1], cw);
      atomicAdd(&acc_g[2], ent);
      atomicAdd(&acc_g[3], 1.f);
      atomicAdd(&acc_g[4], r0);
      atomicAdd(&acc_g[5], r1);
      atomicAdd(&acc_g[6], r2);
    }
  }
}

__global__ __launch_bounds__(64) void nerf_fin(const float* __restrict__ acc,
                                               float* __restrict__ out) {
  if (threadIdx.x == 0) {
    float ls = acc[0] / fmaxf(acc[1], 1e-12f);
    float nv = fmaxf(acc[3], 1.f);
    float le = acc[2] / nv;
    float nmax = fmaxf(acc[6], 1.f);
    float ld = (acc[4] + (1.f / 3.f) * (1.f / nmax) * acc[5]) / nv;
    out[0] = 1.0f * ls;
    out[1] = 0.01f * le;
    out[2] = 0.01f * ld;
  }
}

extern "C" void kernel_launch(void* const* d_in, const int* in_sizes, int n_in,
                              void* d_out, int out_size, void* d_ws, size_t ws_size,
                              hipStream_t stream) {
  const float* density = (const float*)d_in[0];
  const float* semantic = (const float*)d_in[1];
  const float* rays = (const float*)d_in[2];
  const float* bda = (const float*)d_in[3];
  float* out = (float*)d_out;
  float* acc = (float*)d_ws;
  unsigned int* rec = (unsigned int*)((char*)d_ws + 256);
  int nrays = in_sizes[2] / 10;
  int nb = (nrays + RPB - 1) / RPB;

  nerf_zero<<<1, 256, 0, stream>>>(acc);
  if (ws_size >= 256 + REC_BYTES) {
    nerf_repack<<<NVOX / 64, 64, 0, stream>>>(density, semantic, rec);
    nerf_main<1><<<nb, 64 * RPB, 0, stream>>>(density, semantic, rec, rays,
                                              bda, acc, nrays);
  } else {
    nerf_main<0><<<nb, 64 * RPB, 0, stream>>>(density, semantic, rec, rays,
                                              bda, acc, nrays);
  }
  nerf_fin<<<1, 64, 0, stream>>>(acc, out);
}

// Round 4
// 750.434 us; speedup vs baseline: 1.0195x; 1.0094x over previous
//
#include <hip/hip_runtime.h>
#include <math.h>

// NerfHead: fused ray-march + trilinear + online transmittance + 3 losses.
// One wave per ray, 4 rays per 256-thread block.
// d_ws: [0..255] float acc[7]; [256..] optional 24-B voxel records:
//   dword0 = f32 density, dwords1..5 = 17 fp8-e4m3 semantic + 3 pad bytes.
// Records are 8-B aligned (24 = 3*8): three uint2 loads per corner.
// Working model (r1-r3 evidence): gather cost ~ total divergent dword-
// sectors; fp8 records cut 152 -> 48 sectors/sample.

#define DXX 200
#define DYY 200
#define DZZ 16
#define NC 17
#define S_TOT 416
#define N_IN 390
#define CHUNKS 7
#define RPB 4
#define NVOX (DXX * DYY * DZZ)
#define REC_DW 6
#define REC_BYTES ((size_t)NVOX * REC_DW * 4)   // 15,360,000

__constant__ double c_freq[NC] = {1163161.0, 2309034.0, 188743.0, 2997643.0,
  20317180.0, 852476.0, 243808.0, 2457947.0, 497017.0, 2731022.0, 7224789.0,
  214411435.0, 5565043.0, 63191967.0, 76098082.0, 128860031.0, 141625221.0};

__device__ __forceinline__ float iscan_add(float x, int lane) {
#pragma unroll
  for (int off = 1; off < 64; off <<= 1) {
    float y = __shfl_up(x, off);
    if (lane >= off) x += y;
  }
  return x;
}
__device__ __forceinline__ float iscan_mul(float x, int lane) {
#pragma unroll
  for (int off = 1; off < 64; off <<= 1) {
    float y = __shfl_up(x, off);
    if (lane >= off) x *= y;
  }
  return x;
}

// ---------------- fp8 e4m3fn encode/decode ----------------
#if __has_builtin(__builtin_amdgcn_cvt_pk_f32_fp8)
#define HAVE_PK_FP8 1
typedef float f32x2 __attribute__((ext_vector_type(2)));
#endif

__device__ __forceinline__ float dec8b(unsigned b) {
  unsigned s = b >> 7, E = (b >> 3) & 15, M = b & 7;
  float v;
  if (E == 0) v = ldexpf((float)M, -9);
  else v = ldexpf((float)(8 + M), (int)E - 10);
  return s ? -v : v;
}

__device__ __forceinline__ void dec4(unsigned int word, float* o) {
#ifdef HAVE_PK_FP8
  f32x2 lo = __builtin_amdgcn_cvt_pk_f32_fp8((int)word, false);
  f32x2 hi = __builtin_amdgcn_cvt_pk_f32_fp8((int)word, true);
  o[0] = lo[0]; o[1] = lo[1]; o[2] = hi[0]; o[3] = hi[1];
#else
  o[0] = dec8b(word & 0xFF);
  o[1] = dec8b((word >> 8) & 0xFF);
  o[2] = dec8b((word >> 16) & 0xFF);
  o[3] = dec8b((word >> 24) & 0xFF);
#endif
}

__device__ __forceinline__ unsigned enc8(float x) {
#ifdef HAVE_PK_FP8
#if __has_builtin(__builtin_amdgcn_cvt_pk_fp8_f32)
  int r = __builtin_amdgcn_cvt_pk_fp8_f32(x, 0.f, 0, false);
  return (unsigned)r & 0xFF;
#else
  goto manual;
#endif
#endif
#ifndef HAVE_PK_FP8
manual:;
#endif
#if !defined(HAVE_PK_FP8) || !__has_builtin(__builtin_amdgcn_cvt_pk_fp8_f32)
  unsigned bits = __float_as_uint(x);
  unsigned sign = (bits >> 31) & 1;
  int exp = (int)((bits >> 23) & 0xFF) - 127;
  if (((bits >> 23) & 0xFF) == 0xFF) return (sign << 7) | 0x7E;
  float a = fabsf(x);
  unsigned r;
  if (a < ldexpf(1.f, -10)) {
    r = 0;
  } else if (exp < -6) {
    int q = (int)rintf(ldexpf(a, 9));
    if (q >= 8) r = 0x08; else r = (unsigned)q;
  } else {
    int q = (int)rintf(ldexpf(a, 3 - exp));
    if (q >= 16) { exp++; q = 8; }
    int E = exp + 7;
    if (E >= 16) r = 0x7E;
    else r = (unsigned)((E << 3) | (q - 8));
    if (r > 0x7E) r = 0x7E;
  }
  return (sign << 7) | r;
#endif
}

__global__ __launch_bounds__(256) void nerf_zero(float* acc) {
  if (threadIdx.x < 16) acc[threadIdx.x] = 0.f;
}

// ---- repack to 24-B records (launched only when ws_size allows) ----
__global__ __launch_bounds__(64) void nerf_repack(
    const float* __restrict__ density,
    const float* __restrict__ semantic,
    unsigned int* __restrict__ rec) {
  __shared__ float sf[64 * NC];
  __shared__ __align__(16) unsigned int so[64 * REC_DW];
  const int tid = threadIdx.x;
  const size_t v0 = (size_t)blockIdx.x * 64;
  for (int i = tid; i < 64 * NC; i += 64) sf[i] = semantic[v0 * NC + i];
  float d = density[v0 + tid];
  __syncthreads();
  const float* s = &sf[tid * NC];
  unsigned int* o = &so[tid * REC_DW];
  o[0] = __float_as_uint(d);
  unsigned char by[20];
#pragma unroll
  for (int j = 0; j < NC; j++) by[j] = (unsigned char)enc8(s[j]);
  by[17] = 0; by[18] = 0; by[19] = 0;
#pragma unroll
  for (int k = 0; k < 5; k++)
    o[1 + k] = (unsigned)by[4 * k] | ((unsigned)by[4 * k + 1] << 8) |
               ((unsigned)by[4 * k + 2] << 16) | ((unsigned)by[4 * k + 3] << 24);
  __syncthreads();
  uint4* dst = (uint4*)(rec + v0 * REC_DW);
  const uint4* src = (const uint4*)so;
#pragma unroll
  for (int i = tid; i < 64 * REC_DW / 4; i += 64) dst[i] = src[i];
}

template <int PACKED>
__global__ __launch_bounds__(256) void nerf_main(
    const float* __restrict__ density,
    const float* __restrict__ semantic,
    const unsigned int* __restrict__ rec,
    const float* __restrict__ rays,
    const float* __restrict__ bda,
    float* __restrict__ acc_g,
    int nrays) {
  __shared__ float s_t[CHUNKS * 64];
  __shared__ float s_dist[RPB][S_TOT];
  __shared__ unsigned long long s_keep[RPB][CHUNKS];

  const int lane = threadIdx.x & 63;
  const int wv = threadIdx.x >> 6;
  const int ray = blockIdx.x * RPB + wv;

  const double BG = (double)(1.0f / 39.0f);
  const float BGf = (float)BG;
  const float DTH = (float)((2.0 + 2.0 * BG) / 200.0 * 0.5 * 0.95);
  const float xminf = (float)(-1.0 - BG);
  const float xmaxf = (float)(1.0 + BG);
  const float zf = 6.4f / 80.0f;
  const float sxy = 199.0f / (xmaxf - xminf);
  const float szc = 15.0f / (zf + zf);
  const float ACTS = -13.815509557964274f;

  for (int i = threadIdx.x; i < CHUNKS * 64; i += 256) {
    double td;
    if (i < N_IN) {
      td = (2.0 * i + 1.0) / 390.0;
    } else {
      int j = i - N_IN;
      const double stp = (1.0 / 64.0 - 1.0) / 26.0;
      double l0 = 1.0 + j * stp;
      double l1 = (j + 1 >= 26) ? (1.0 / 64.0) : (1.0 + (j + 1) * stp);
      td = 1.0 / l0 + 1.0 / l1;
    }
    s_t[i] = (float)td;
  }
  __syncthreads();

  bool doit = false;
  float rox = 0, roy = 0, roz = 0, rdx = 0, rdy = 0, rdz = 0;
  float b00 = 0, b01 = 0, b02 = 0, b10 = 0, b11 = 0, b12 = 0, b20 = 0, b21 = 0, b22 = 0;
  int ysem = 0;
  if (ray < nrays) {
    const float* rp = rays + (size_t)ray * 10;
    float dep = rp[2];
    doit = (dep > 0.f) && (dep <= 52.f);
    ysem = (int)rp[3];
    ysem = ysem < 0 ? 0 : (ysem > NC - 1 ? NC - 1 : ysem);
    const float czc = (-1.0f + 5.4f) * 0.5f;
    rox = rp[4] / 39.0f;
    roy = rp[5] / 39.0f;
    roz = (rp[6] - czc) / 39.0f;
    float d0 = rp[7], d1 = rp[8], d2 = rp[9];
    float rn = sqrtf(d0 * d0 + d1 * d1 + d2 * d2);
    rdx = d0 / rn; rdy = d1 / rn; rdz = d2 / rn;
    b00 = bda[0]; b01 = bda[1]; b02 = bda[2];
    b10 = bda[3]; b11 = bda[4]; b12 = bda[5];
    b20 = bda[6]; b21 = bda[7]; b22 = bda[8];
  }

  auto compute_pt = [&](int s, float& tx, float& ty, float& tz, float& tt,
                        bool& inner) {
    tt = s_t[s];
    float qx = rox + rdx * tt;
    float qy = roy + rdy * tt;
    float qz = roz + rdz * tt;
    float nr = sqrtf(qx * qx + qy * qy + qz * qz);
    inner = (nr <= 1.0f) && (s < S_TOT);
    if (nr > 1.0f) {
      float sc = (1.0f + BGf - BGf / nr) / nr;
      qx *= sc; qy *= sc; qz *= sc;
    }
    tx = b00 * qx + b01 * qy + b02 * qz;
    ty = b10 * qx + b11 * qy + b12 * qz;
    tz = b20 * qx + b21 * qy + b22 * qz;
  };

  // ---- phase A/B: pts, inner ballot, consecutive distances -> LDS ----
  if (doit) {
    for (int c = 0; c < CHUNKS; c++) {
      int s = c * 64 + lane;
      float tx, ty, tz, tt; bool inner;
      compute_pt(s, tx, ty, tz, tt, inner);
      unsigned long long bal = __ballot(inner);
      if (lane == 0) s_keep[wv][c] = bal;
      float nx = __shfl(tx, lane + 1);
      float ny = __shfl(ty, lane + 1);
      float nz = __shfl(tz, lane + 1);
      if (c < CHUNKS - 1) {
        float hx, hy, hz, ht; bool hi;
        compute_pt((c + 1) * 64, hx, hy, hz, ht, hi);
        if (lane == 63) { nx = hx; ny = hy; nz = hz; }
      }
      if (s < S_TOT - 1) {
        float ex = nx - tx, ey = ny - ty, ez = nz - tz;
        s_dist[wv][s] = sqrtf(ex * ex + ey * ey + ez * ez);
      }
    }
  }
  __syncthreads();

  // ---- phase C: sequential resetting distance scan -> keep mask ----
  if (doit && lane == 0) {
    float cum = 0.f;
    for (int c = 0; c < CHUNKS; c++) {
      unsigned long long k = s_keep[wv][c];
      int b0 = (c == 0) ? 1 : 0;
      for (int b = b0; b < 64; b++) {
        int s = c * 64 + b;
        if (s >= S_TOT) break;
        cum += s_dist[wv][s - 1];
        if (cum > DTH) { cum = 0.f; k |= (1ull << b); }
      }
      s_keep[wv][c] = k;
    }
  }
  __syncthreads();

  // ---- phase D/E/F ----
  float out_sem[NC];
  if (doit) {
#pragma unroll
    for (int j = 0; j < NC; j++) out_sem[j] = 0.f;
    float carry = 1.f, carryW = 0.f, carryWM = 0.f;
    float sum_bi = 0.f, sum_w2 = 0.f, pkcf = 0.f;

    for (int c = 0; c < CHUNKS; c++) {
      int s = c * 64 + lane;
      float tx, ty, tz, tt; bool inner;
      compute_pt(s, tx, ty, tz, tt, inner);
      float m_ = 1.0f - 1.0f / (1.0f + tt);
      bool keep = (s_keep[wv][c] >> lane) & 1ull;

      float a = 0.f;
      int ix = 0, iy = 0, iz = 0;
      float fx = 0.f, fy = 0.f, fz = 0.f;
      bool any = false;
      float semf[NC];
      if (PACKED) {
#pragma unroll
        for (int j = 0; j < NC; j++) semf[j] = 0.f;
      }

      if (keep) {
        float gx = (tx - xminf) * sxy;
        float gy = (ty - xminf) * sxy;
        float gz = (tz + zf) * szc;
        float hx = floorf(gx), hy = floorf(gy), hz = floorf(gz);
        ix = (int)hx; iy = (int)hy; iz = (int)hz;
        fx = gx - hx; fy = gy - hy; fz = gz - hz;
        any = (ix >= -1) && (ix <= DXX - 1) && (iy >= -1) &&
              (iy <= DYY - 1) && (iz >= -1) && (iz <= DZZ - 1);
        float dens = 0.f;
        if (any) {
          int x0 = ix < 0 ? 0 : ix;
          int x1 = (ix + 1 > DXX - 1) ? DXX - 1 : ix + 1;
          int y0 = iy < 0 ? 0 : iy;
          int y1 = (iy + 1 > DYY - 1) ? DYY - 1 : iy + 1;
          int z0 = iz < 0 ? 0 : iz;
          int z1 = (iz + 1 > DZZ - 1) ? DZZ - 1 : iz + 1;
          float wxm[2] = {(ix >= 0) ? 1.f - fx : 0.f,
                          (ix + 1 <= DXX - 1) ? fx : 0.f};
          float wym[2] = {(iy >= 0) ? 1.f - fy : 0.f,
                          (iy + 1 <= DYY - 1) ? fy : 0.f};
          float wzm[2] = {(iz >= 0) ? 1.f - fz : 0.f,
                          (iz + 1 <= DZZ - 1) ? fz : 0.f};
          unsigned int xs[2] = {(unsigned)(x0 * (DYY * DZZ)), (unsigned)(x1 * (DYY * DZZ))};
          unsigned int ys[2] = {(unsigned)(y0 * DZZ), (unsigned)(y1 * DZZ)};
          unsigned int zs[2] = {(unsigned)z0, (unsigned)z1};
          if (PACKED) {
            // fused density+fp8-semantic gather: 3x uint2 per corner
#pragma unroll
            for (int dx = 0; dx < 2; dx++) {
#pragma unroll
              for (int dy = 0; dy < 2; dy++) {
#pragma unroll
                for (int dz = 0; dz < 2; dz++) {
                  float wc = wxm[dx] * wym[dy] * wzm[dz];
                  unsigned int vox = xs[dx] + ys[dy] + zs[dz];
                  const uint2* rp = (const uint2*)(rec + (size_t)vox * REC_DW);
                  uint2 q0 = rp[0];
                  uint2 q1 = rp[1];
                  uint2 q2 = rp[2];
                  dens = fmaf(wc, __uint_as_float(q0.x), dens);
                  float sv[20];
                  dec4(q0.y, sv);
                  dec4(q1.x, sv + 4);
                  dec4(q1.y, sv + 8);
                  dec4(q2.x, sv + 12);
                  dec4(q2.y, sv + 16);
#pragma unroll
                  for (int j = 0; j < NC; j++)
                    semf[j] = fmaf(wc, sv[j], semf[j]);
                }
              }
            }
          } else {
            dens += wxm[0] * wym[0] * wzm[0] * density[(size_t)(xs[0] + ys[0] + zs[0])];
            dens += wxm[0] * wym[0] * wzm[1] * density[(size_t)(xs[0] + ys[0] + zs[1])];
            dens += wxm[0] * wym[1] * wzm[0] * density[(size_t)(xs[0] + ys[1] + zs[0])];
            dens += wxm[0] * wym[1] * wzm[1] * density[(size_t)(xs[0] + ys[1] + zs[1])];
            dens += wxm[1] * wym[0] * wzm[0] * density[(size_t)(xs[1] + ys[0] + zs[0])];
            dens += wxm[1] * wym[0] * wzm[1] * density[(size_t)(xs[1] + ys[0] + zs[1])];
            dens += wxm[1] * wym[1] * wzm[0] * density[(size_t)(xs[1] + ys[1] + zs[0])];
            dens += wxm[1] * wym[1] * wzm[1] * density[(size_t)(xs[1] + ys[1] + zs[1])];
          }
        }
        float u = expf(dens + ACTS);
        a = -expm1f(-0.5f * log1pf(u));
        if (!(a > 1e-7f)) a = 0.f;
      }

      // transmittance cumprod (chunked scan + carry)
      float om = 1.f - a;
      float ip = iscan_mul(om, lane);
      float ex = __shfl_up(ip, 1); if (lane == 0) ex = 1.f;
      float wgt = a * carry * ex;
      carry *= __shfl(ip, 63);
      float w = (wgt > 1e-7f) ? wgt : 0.f;
      if (w > 0.f) pkcf += 1.f;

      // distortion-loss cumsums (exclusive)
      float wm = w * m_;
      float isw = iscan_add(w, lane);
      float iswm = iscan_add(wm, lane);
      float exw = __shfl_up(isw, 1);  if (lane == 0) exw = 0.f;
      float exwm = __shfl_up(iswm, 1); if (lane == 0) exwm = 0.f;
      sum_bi += 2.f * w * (m_ * (carryW + exw) - (carryWM + exwm));
      sum_w2 += w * w;
      carryW += __shfl(isw, 63);
      carryWM += __shfl(iswm, 63);

      // semantic accumulation
      if (w > 0.f) {
        if (PACKED) {
#pragma unroll
          for (int j = 0; j < NC; j++)
            out_sem[j] = fmaf(w, semf[j], out_sem[j]);
        } else if (any) {
          int x0 = ix < 0 ? 0 : ix;
          int x1 = (ix + 1 > DXX - 1) ? DXX - 1 : ix + 1;
          int y0 = iy < 0 ? 0 : iy;
          int y1 = (iy + 1 > DYY - 1) ? DYY - 1 : iy + 1;
          int z0 = iz < 0 ? 0 : iz;
          int z1 = (iz + 1 > DZZ - 1) ? DZZ - 1 : iz + 1;
          float wxm[2] = {(ix >= 0) ? 1.f - fx : 0.f,
                          (ix + 1 <= DXX - 1) ? fx : 0.f};
          float wym[2] = {(iy >= 0) ? 1.f - fy : 0.f,
                          (iy + 1 <= DYY - 1) ? fy : 0.f};
          float wzm[2] = {(iz >= 0) ? 1.f - fz : 0.f,
                          (iz + 1 <= DZZ - 1) ? fz : 0.f};
          unsigned int xs[2] = {(unsigned)(x0 * (DYY * DZZ)), (unsigned)(x1 * (DYY * DZZ))};
          unsigned int ys[2] = {(unsigned)(y0 * DZZ), (unsigned)(y1 * DZZ)};
          unsigned int zs[2] = {(unsigned)z0, (unsigned)z1};
#pragma unroll
          for (int dx = 0; dx < 2; dx++) {
#pragma unroll
            for (int dy = 0; dy < 2; dy++) {
#pragma unroll
              for (int dz = 0; dz < 2; dz++) {
                float wcw = w * wxm[dx] * wym[dy] * wzm[dz];
                unsigned int vox = xs[dx] + ys[dy] + zs[dz];
                const float* sp = semantic + (size_t)vox * NC;
#pragma unroll
                for (int j = 0; j < NC; j++)
                  out_sem[j] = fmaf(wcw, sp[j], out_sem[j]);
              }
            }
          }
        }
      }
    }

    // ---- wave reductions + per-ray epilogue + atomics ----
    float r0 = sum_bi, r1 = sum_w2, r2 = pkcf;
#pragma unroll
    for (int off = 32; off >= 1; off >>= 1) {
      r0 += __shfl_xor(r0, off);
      r1 += __shfl_xor(r1, off);
      r2 += __shfl_xor(r2, off);
#pragma unroll
      for (int j = 0; j < NC; j++) out_sem[j] += __shfl_xor(out_sem[j], off);
    }
    if (lane == 0) {
      float M = out_sem[0];
#pragma unroll
      for (int j = 1; j < NC; j++) M = fmaxf(M, out_sem[j]);
      float se = 0.f;
#pragma unroll
      for (int j = 0; j < NC; j++) se += expf(out_sem[j] - M);
      float lse = M + logf(se);
      float sy = 0.f;
#pragma unroll
      for (int j = 0; j < NC; j++) if (j == ysem) sy = out_sem[j];
      float nll = lse - sy;
      float cw = (float)(1.0 / log(c_freq[ysem] + 0.001));
      float p = fminf(fmaxf(carry, 1e-6f), 1.0f - 1e-6f);
      float ent = -(p * logf(p) + (1.f - p) * logf(1.f - p));
      atomicAdd(&acc_g[0], cw * nll);
      atomicAdd(&acc_g[1], cw);
      atomicAdd(&acc_g[2], ent);
      atomicAdd(&acc_g[3], 1.f);
      atomicAdd(&acc_g[4], r0);
      atomicAdd(&acc_g[5], r1);
      atomicAdd(&acc_g[6], r2);
    }
  }
}

__global__ __launch_bounds__(64) void nerf_fin(const float* __restrict__ acc,
                                               float* __restrict__ out) {
  if (threadIdx.x == 0) {
    float ls = acc[0] / fmaxf(acc[1], 1e-12f);
    float nv = fmaxf(acc[3], 1.f);
    float le = acc[2] / nv;
    float nmax = fmaxf(acc[6], 1.f);
    float ld = (acc[4] + (1.f / 3.f) * (1.f / nmax) * acc[5]) / nv;
    out[0] = 1.0f * ls;
    out[1] = 0.01f * le;
    out[2] = 0.01f * ld;
  }
}

extern "C" void kernel_launch(void* const* d_in, const int* in_sizes, int n_in,
                              void* d_out, int out_size, void* d_ws, size_t ws_size,
                              hipStream_t stream) {
  const float* density = (const float*)d_in[0];
  const float* semantic = (const float*)d_in[1];
  const float* rays = (const float*)d_in[2];
  const float* bda = (const float*)d_in[3];
  float* out = (float*)d_out;
  float* acc = (float*)d_ws;
  unsigned int* rec = (unsigned int*)((char*)d_ws + 256);
  int nrays = in_sizes[2] / 10;
  int nb = (nrays + RPB - 1) / RPB;

  nerf_zero<<<1, 256, 0, stream>>>(acc);
  if (ws_size >= 256 + REC_BYTES) {
    nerf_repack<<<NVOX / 64, 64, 0, stream>>>(density, semantic, rec);
    nerf_main<1><<<nb, 64 * RPB, 0, stream>>>(density, semantic, rec, rays,
                                              bda, acc, nrays);
  } else {
    nerf_main<0><<<nb, 64 * RPB, 0, stream>>>(density, semantic, rec, rays,
                                              bda, acc, nrays);
  }
  nerf_fin<<<1, 64, 0, stream>>>(acc, out);
}